// Round 10
// baseline (101.538 us; speedup 1.0000x reference)
//
#include <hip/hip_runtime.h>
#include <cstddef>

// YOLO decode: out[b, ((h*W+w)*3+a), attr] = f(x[b, a*85+attr, h, w])
//   attr 0: (sigmoid(v) + w) * stride
//   attr 1: (sigmoid(v) + h) * stride
//   attr 2: exp(v) * anchor_w_px
//   attr 3: exp(v) * anchor_h_px
//   attr 4: sigmoid(v)
//   attr>=5: sigmoid(idf[attr-5] * v)
//
// R5 structure (512 thr, 32-px tile, transform-at-staging, LDS [p][c] stride
// 255, aligned ds_read_b128 + dwordx4 out) + PERSISTENT grid (1024 blocks =
// 4/CU LDS limit, grid-stride over tiles -> no dispatch tail rounds).
// R9 lesson: NO nontemporal stores — adjacent tiles share 64B output lines
// (batch bases are 4B*3b-misaligned), nt forced partial-line RMW at HBM
// (WRITE_SIZE 121->197 MB). Plain cached stores let L2 merge line sharers.

#define NATTR 85
#define NCH 255
#define TILE 32
#define NSTG (NCH * (TILE / 4))  // 2040 staging quads per full tile
#define NTHR 512
#define GRID 1024

static constexpr int TOTROWS = (76 * 76 + 38 * 38 + 19 * 19) * 3;  // 22743

static __device__ __forceinline__ float sigmoidf_(float x) {
  return 1.0f / (1.0f + __expf(-x));
}

template <int SCALE>
struct Cfg {
  static constexpr int W = (SCALE == 0) ? 76 : (SCALE == 1) ? 38 : 19;
  static constexpr int HW = W * W;
  static constexpr int TILES = (HW + TILE - 1) / TILE;  // 181 / 46 / 12
  static constexpr float STRIDE = 608.0f / (float)W;
  static constexpr int ROWBASE =
      (SCALE == 0) ? 0 : (SCALE == 1) ? 76 * 76 * 3 : (76 * 76 * 3 + 38 * 38 * 3);
  static constexpr float AW0 = (SCALE == 0) ? 10.f : (SCALE == 1) ? 30.f : 116.f;
  static constexpr float AW1 = (SCALE == 0) ? 16.f : (SCALE == 1) ? 62.f : 156.f;
  static constexpr float AW2 = (SCALE == 0) ? 33.f : (SCALE == 1) ? 59.f : 373.f;
  static constexpr float AH0 = (SCALE == 0) ? 13.f : (SCALE == 1) ? 61.f : 90.f;
  static constexpr float AH1 = (SCALE == 0) ? 30.f : (SCALE == 1) ? 45.f : 198.f;
  static constexpr float AH2 = (SCALE == 0) ? 23.f : (SCALE == 1) ? 119.f : 326.f;
};

template <int SCALE>
static __device__ __forceinline__ float xf(int a, int attr, int p, float v,
                                           const float* __restrict__ sidf) {
  using C = Cfg<SCALE>;
  if (attr >= 5) return sigmoidf_(sidf[attr - 5] * v);  // 80/85 channels
  if (attr == 4) return sigmoidf_(v);
  if (attr == 2) {
    const float aw = (a == 0) ? C::AW0 : (a == 1) ? C::AW1 : C::AW2;
    return __expf(v) * aw;
  }
  if (attr == 3) {
    const float ah = (a == 0) ? C::AH0 : (a == 1) ? C::AH1 : C::AH2;
    return __expf(v) * ah;
  }
  const int h = p / C::W;  // constexpr W -> magic mul
  const int w = p - h * C::W;
  return (sigmoidf_(v) + (float)((attr == 0) ? w : h)) * C::STRIDE;
}

struct TState {
  size_t off;
  int np, head, s;
};

// stage = init + global load + transform + LDS write (no barrier inside)
template <int SCALE>
static __device__ __forceinline__ void tile_stage(int idx, const float* __restrict__ x,
                                                  const float* __restrict__ sidf,
                                                  float* __restrict__ lds, TState& st) {
  using C = Cfg<SCALE>;
  const int b = idx / C::TILES;
  const int t = idx - b * C::TILES;
  const int p0 = t * TILE;
  const int rem = C::HW - p0;
  st.np = rem < TILE ? rem : TILE;
  st.off = ((size_t)b * TOTROWS + C::ROWBASE + (size_t)p0 * 3) * NATTR;
  st.head = (int)((4 - (st.off & 3)) & 3);
  st.s = (4 - st.head) & 3;  // LDS shift so lds[s+head] is 16B-aligned
  const float* src = x + (size_t)b * ((size_t)C::HW * NCH) + p0;

  if ((C::HW % 4 == 0) && st.np == TILE) {
    float4 r[4];
#pragma unroll
    for (int k = 0; k < 4; ++k) {
      int i = (int)threadIdx.x + NTHR * k;
      i = i < NSTG ? i : NSTG - 1;  // clamp: branch-free in-bounds load
      const int c = i >> 3, v = i & 7;
      r[k] = *reinterpret_cast<const float4*>(src + (size_t)c * C::HW + 4 * v);
    }
#pragma unroll
    for (int k = 0; k < 4; ++k) {
      const int i = (int)threadIdx.x + NTHR * k;
      if (i < NSTG) {
        const int c = i >> 3, v = i & 7;
        const int a = c / NATTR;
        const int attr = c - a * NATTR;
        const int pb = p0 + 4 * v;
        float* dl = lds + st.s + (4 * v) * NCH + c;  // [p][c], stride 255
        dl[0]       = xf<SCALE>(a, attr, pb + 0, r[k].x, sidf);
        dl[NCH]     = xf<SCALE>(a, attr, pb + 1, r[k].y, sidf);
        dl[2 * NCH] = xf<SCALE>(a, attr, pb + 2, r[k].z, sidf);
        dl[3 * NCH] = xf<SCALE>(a, attr, pb + 3, r[k].w, sidf);
      }
    }
  } else {
    // odd-HW (scale 2) or partial tile: scalar guarded
    for (int i = threadIdx.x; i < NCH * TILE; i += NTHR) {
      const int c = i >> 5, p = i & 31;
      if (p < st.np) {
        const int a = c / NATTR;
        const int attr = c - a * NATTR;
        const float v = src[(size_t)c * C::HW + p];
        lds[st.s + p * NCH + c] = xf<SCALE>(a, attr, p0 + p, v, sidf);
      }
    }
  }
}

static __device__ __forceinline__ void tile_read(const TState& st,
                                                 const float* __restrict__ lds,
                                                 float4 (&tt)[4], float& hv, float& tv) {
  const int total = st.np * NCH;
  if ((st.np & 3) == 0) {
    const int nvec = (total - st.head) >> 2;
    const float4* lv = reinterpret_cast<const float4*>(lds + st.s + st.head);  // aligned
    if ((int)threadIdx.x < st.head) hv = lds[st.s + threadIdx.x];
#pragma unroll
    for (int k = 0; k < 4; ++k) {
      int v = (int)threadIdx.x + NTHR * k;
      v = v < nvec ? v : nvec - 1;
      tt[k] = lv[v];
    }
    const int done = st.head + 4 * nvec;
    if ((int)threadIdx.x < total - done) tv = lds[st.s + done + threadIdx.x];
  } else {
    float* tf = reinterpret_cast<float*>(tt);
#pragma unroll
    for (int m = 0; m < 5; ++m) {
      const int j = (int)threadIdx.x + NTHR * m;
      if (j < total) tf[m] = lds[st.s + j];
    }
  }
}

static __device__ __forceinline__ void tile_store(const TState& st, float4 (&tt)[4],
                                                  float hv, float tv,
                                                  float* __restrict__ out) {
  const int total = st.np * NCH;
  float* dst = out + st.off;
  if ((st.np & 3) == 0) {
    const int nvec = (total - st.head) >> 2;
    if ((int)threadIdx.x < st.head) dst[threadIdx.x] = hv;
#pragma unroll
    for (int k = 0; k < 4; ++k) {
      const int v = (int)threadIdx.x + NTHR * k;
      if (v < nvec) *reinterpret_cast<float4*>(dst + st.head + 4 * v) = tt[k];
    }
    const int done = st.head + 4 * nvec;
    if ((int)threadIdx.x < total - done) dst[done + threadIdx.x] = tv;
  } else {
    const float* tf = reinterpret_cast<const float*>(tt);
#pragma unroll
    for (int m = 0; m < 5; ++m) {
      const int j = (int)threadIdx.x + NTHR * m;
      if (j < total) dst[j] = tf[m];
    }
  }
}

__global__ __launch_bounds__(NTHR, 8) void yolo_all(
    const float* __restrict__ x0, const float* __restrict__ x1,
    const float* __restrict__ x2, const float* __restrict__ idf,
    float* __restrict__ out, int bs) {
  __shared__ __align__(16) float lds[TILE * NCH + 4];
  __shared__ float sidf[80];
  if (threadIdx.x < 80) sidf[threadIdx.x] = idf[threadIdx.x];
  __syncthreads();

  const int nb0 = Cfg<0>::TILES * bs;
  const int nb1 = Cfg<1>::TILES * bs;
  const int ntiles = nb0 + nb1 + Cfg<2>::TILES * bs;

  // Persistent blocks: grid-stride over tiles. Scale branch is block-uniform
  // (function of tile id), so the barriers below are safe.
  for (int t = blockIdx.x; t < ntiles; t += GRID) {
    TState st;
    if (t < nb0) {
      tile_stage<0>(t, x0, sidf, lds, st);
    } else if (t < nb0 + nb1) {
      tile_stage<1>(t - nb0, x1, sidf, lds, st);
    } else {
      tile_stage<2>(t - nb0 - nb1, x2, sidf, lds, st);
    }
    __syncthreads();  // LDS image visible
    float4 tt[4];
    float hv = 0.f, tv = 0.f;
    tile_read(st, lds, tt, hv, tv);
    __syncthreads();  // all reads done -> buffer free for next iteration
    tile_store(st, tt, hv, tv, out);  // next iter's loads follow immediately
  }
}

extern "C" void kernel_launch(void* const* d_in, const int* in_sizes, int n_in,
                              void* d_out, int out_size, void* d_ws, size_t ws_size,
                              hipStream_t stream) {
  const float* x0 = (const float*)d_in[0];
  const float* x1 = (const float*)d_in[1];
  const float* x2 = (const float*)d_in[2];
  const float* idf = (const float*)d_in[3];
  float* out = (float*)d_out;

  const int bs = in_sizes[0] / (NCH * 76 * 76);  // 16
  const int ntiles = (Cfg<0>::TILES + Cfg<1>::TILES + Cfg<2>::TILES) * bs;  // 3824
  const int nb = ntiles < GRID ? ntiles : GRID;

  yolo_all<<<dim3(nb), dim3(NTHR), 0, stream>>>(x0, x1, x2, idf, out, bs);
}

// Round 11
// 47.737 us; speedup vs baseline: 2.1270x; 2.1270x over previous
//
#include <hip/hip_runtime.h>
#include <cstddef>

// YOLO decode: out[b, ((h*W+w)*3+a), attr] = f(x[b, a*85+attr, h, w])
//   attr 0: (sigmoid(v) + w) * stride
//   attr 1: (sigmoid(v) + h) * stride
//   attr 2: exp(v) * anchor_w_px
//   attr 3: exp(v) * anchor_h_px
//   attr 4: sigmoid(v)
//   attr>=5: sigmoid(idf[attr-5] * v)
//
// R5 structure (best known): 512 thr, one 32-px tile per block, transform at
// staging, LDS [p][c] stride 255 (conflict-free), image pre-shifted so
// copy-out is aligned ds_read_b128 + aligned dwordx4 stores.
// R9/R10 lessons: NO nontemporal stores, NO persistent grid — both inflate
// WRITE_SIZE (197/235 vs 121 MB); the write stream relies on dispatch-order
// synchronization of neighboring-tile blocks for L2 line merging.
// R11: + bijective XCD-chunked swizzle so each output chunk (and its
// tile-boundary shared lines) is owned by exactly ONE XCD's L2.

#define NATTR 85
#define NCH 255
#define TILE 32        // pixels per block
#define QPT 8          // float4 quads per channel tile (TILE/4)
#define NSTG (NCH * QPT)  // 2040 staging quads per full tile
#define NTHR 512
#define NXCD 8

static constexpr int TOTROWS = (76 * 76 + 38 * 38 + 19 * 19) * 3;  // 22743

static __device__ __forceinline__ float sigmoidf_(float x) {
  return 1.0f / (1.0f + __expf(-x));
}

template <int SCALE>
struct Cfg {
  static constexpr int W = (SCALE == 0) ? 76 : (SCALE == 1) ? 38 : 19;
  static constexpr int HW = W * W;
  static constexpr int TILES = (HW + TILE - 1) / TILE;  // 181 / 46 / 12
  static constexpr float STRIDE = 608.0f / (float)W;
  static constexpr int ROWBASE =
      (SCALE == 0) ? 0 : (SCALE == 1) ? 76 * 76 * 3 : (76 * 76 * 3 + 38 * 38 * 3);
  static constexpr float AW0 = (SCALE == 0) ? 10.f : (SCALE == 1) ? 30.f : 116.f;
  static constexpr float AW1 = (SCALE == 0) ? 16.f : (SCALE == 1) ? 62.f : 156.f;
  static constexpr float AW2 = (SCALE == 0) ? 33.f : (SCALE == 1) ? 59.f : 373.f;
  static constexpr float AH0 = (SCALE == 0) ? 13.f : (SCALE == 1) ? 61.f : 90.f;
  static constexpr float AH1 = (SCALE == 0) ? 30.f : (SCALE == 1) ? 45.f : 198.f;
  static constexpr float AH2 = (SCALE == 0) ? 23.f : (SCALE == 1) ? 119.f : 326.f;
};

template <int SCALE>
static __device__ __forceinline__ float xf(int a, int attr, int p, float v,
                                           const float* __restrict__ sidf) {
  using C = Cfg<SCALE>;
  if (attr >= 5) return sigmoidf_(sidf[attr - 5] * v);  // 80/85 channels
  if (attr == 4) return sigmoidf_(v);
  if (attr == 2) {
    const float aw = (a == 0) ? C::AW0 : (a == 1) ? C::AW1 : C::AW2;
    return __expf(v) * aw;
  }
  if (attr == 3) {
    const float ah = (a == 0) ? C::AH0 : (a == 1) ? C::AH1 : C::AH2;
    return __expf(v) * ah;
  }
  const int h = p / C::W;  // constexpr W -> magic mul
  const int w = p - h * C::W;
  return (sigmoidf_(v) + (float)((attr == 0) ? w : h)) * C::STRIDE;
}

template <int SCALE>
static __device__ __forceinline__ void decode_tile(
    int b, int t, const float* __restrict__ x, float* __restrict__ out,
    const float* __restrict__ sidf, float* __restrict__ lds) {
  using C = Cfg<SCALE>;
  const int p0 = t * TILE;
  const int rem = C::HW - p0;
  const int np = rem < TILE ? rem : TILE;
  const size_t off = ((size_t)b * TOTROWS + C::ROWBASE + (size_t)p0 * 3) * NATTR;
  const int head = (int)((4 - (off & 3)) & 3);
  const int s = (4 - head) & 3;  // LDS shift so lds[s+head] is 16B-aligned
  const float* src = x + (size_t)b * ((size_t)C::HW * NCH) + p0;

  if ((C::HW % 4 == 0) && np == TILE) {
    // full tile: thread owns (channel c, quad v); 8 consecutive lanes share a
    // channel -> 128B contiguous per channel per wave-load
    float4 r[4];
    int cc[4], vv[4];
    bool act[4];
#pragma unroll
    for (int k = 0; k < 4; ++k) {
      int i = (int)threadIdx.x + NTHR * k;
      act[k] = i < NSTG;
      i = act[k] ? i : (NSTG - 1);  // clamp: branch-free in-bounds load
      cc[k] = i >> 3;
      vv[k] = i & 7;
      r[k] = *reinterpret_cast<const float4*>(src + (size_t)cc[k] * C::HW + 4 * vv[k]);
    }
#pragma unroll
    for (int k = 0; k < 4; ++k) {
      if (act[k]) {
        const int c = cc[k];
        const int a = c / NATTR;
        const int attr = c - a * NATTR;
        const int pb = p0 + 4 * vv[k];
        float* dl = lds + s + (4 * vv[k]) * NCH + c;  // [p][c], stride 255
        dl[0]       = xf<SCALE>(a, attr, pb + 0, r[k].x, sidf);
        dl[NCH]     = xf<SCALE>(a, attr, pb + 1, r[k].y, sidf);
        dl[2 * NCH] = xf<SCALE>(a, attr, pb + 2, r[k].z, sidf);
        dl[3 * NCH] = xf<SCALE>(a, attr, pb + 3, r[k].w, sidf);
      }
    }
  } else {
    // tail / odd-HW tile: scalar guarded (consecutive lanes -> consecutive p)
    for (int i = threadIdx.x; i < NCH * TILE; i += NTHR) {
      const int c = i >> 5;
      const int p = i & 31;
      if (p < np) {
        const int a = c / NATTR;
        const int attr = c - a * NATTR;
        const float v = src[(size_t)c * C::HW + p];
        lds[s + p * NCH + c] = xf<SCALE>(a, attr, p0 + p, v, sidf);
      }
    }
  }
  __syncthreads();

  float* dst = out + off;
  const int total = np * NCH;

  if (np == TILE) {
    if (threadIdx.x < head) dst[threadIdx.x] = lds[s + threadIdx.x];
    const int nvec = (total - head) >> 2;  // 2040 or 2039
    const float4* lv = reinterpret_cast<const float4*>(lds + s + head);  // aligned
    float4 tt[4];
    int vi[4];
    bool av[4];
#pragma unroll
    for (int k = 0; k < 4; ++k) {
      int v = (int)threadIdx.x + NTHR * k;
      av[k] = v < nvec;
      vi[k] = av[k] ? v : (nvec - 1);
      tt[k] = lv[vi[k]];
    }
#pragma unroll
    for (int k = 0; k < 4; ++k) {
      if (av[k]) *reinterpret_cast<float4*>(dst + head + 4 * vi[k]) = tt[k];
    }
    const int done = head + 4 * nvec;
    if (threadIdx.x < total - done) dst[done + threadIdx.x] = lds[s + done + threadIdx.x];
  } else {
    for (int j = threadIdx.x; j < total; j += NTHR) dst[j] = lds[s + j];
  }
}

__global__ __launch_bounds__(NTHR, 8) void yolo_all(
    const float* __restrict__ x0, const float* __restrict__ x1,
    const float* __restrict__ x2, const float* __restrict__ idf,
    float* __restrict__ out, int bs) {
  __shared__ __align__(16) float lds[TILE * NCH + 4];
  __shared__ float sidf[80];
  if (threadIdx.x < 80) sidf[threadIdx.x] = idf[threadIdx.x];
  __syncthreads();

  const int nb0 = Cfg<0>::TILES * bs;
  const int nb1 = Cfg<1>::TILES * bs;
  const int ntiles = nb0 + nb1 + Cfg<2>::TILES * bs;  // 3824 (bs=16), % 8 == 0

  // Bijective XCD-chunked swizzle: XCD x (dispatch round-robin bid % 8) owns
  // the contiguous tile chunk [x*cpx, (x+1)*cpx) -> every output line has
  // exactly one L2 owner. ntiles % NXCD == 0 for bs=16 -> clean chunks.
  int blk = blockIdx.x;
  if ((ntiles & (NXCD - 1)) == 0) {
    const int cpx = ntiles / NXCD;
    blk = (blk & (NXCD - 1)) * cpx + (blk >> 3);
  }

  if (blk < nb0) {
    decode_tile<0>(blk / Cfg<0>::TILES, blk % Cfg<0>::TILES, x0, out, sidf, lds);
  } else if (blk < nb0 + nb1) {
    blk -= nb0;
    decode_tile<1>(blk / Cfg<1>::TILES, blk % Cfg<1>::TILES, x1, out, sidf, lds);
  } else {
    blk -= nb0 + nb1;
    decode_tile<2>(blk / Cfg<2>::TILES, blk % Cfg<2>::TILES, x2, out, sidf, lds);
  }
}

extern "C" void kernel_launch(void* const* d_in, const int* in_sizes, int n_in,
                              void* d_out, int out_size, void* d_ws, size_t ws_size,
                              hipStream_t stream) {
  const float* x0 = (const float*)d_in[0];
  const float* x1 = (const float*)d_in[1];
  const float* x2 = (const float*)d_in[2];
  const float* idf = (const float*)d_in[3];
  float* out = (float*)d_out;

  const int bs = in_sizes[0] / (NCH * 76 * 76);  // 16
  const int nb = (Cfg<0>::TILES + Cfg<1>::TILES + Cfg<2>::TILES) * bs;  // 239*bs

  yolo_all<<<dim3(nb), dim3(NTHR), 0, stream>>>(x0, x1, x2, idf, out, bs);
}

// Round 12
// 46.540 us; speedup vs baseline: 2.1817x; 1.0257x over previous
//
#include <hip/hip_runtime.h>
#include <cstddef>

// YOLO decode: out[b, ((h*W+w)*3+a), attr] = f(x[b, a*85+attr, h, w])
//   attr 0: (sigmoid(v) + w) * stride
//   attr 1: (sigmoid(v) + h) * stride
//   attr 2: exp(v) * anchor_w_px
//   attr 3: exp(v) * anchor_h_px
//   attr 4: sigmoid(v)
//   attr>=5: sigmoid(idf[attr-5] * v)
//
// R11 structure (best: transform-at-staging, LDS [p][c] stride 255, aligned
// ds_read_b128 + dwordx4 out, bijective XCD-chunked block swizzle) scaled to
// TILE=64 / 1024-thread blocks: 16 lanes per channel -> 256B contiguous per
// channel per wave-load; 1920 blocks (half of R11); LDS 65.3KB -> 2 blocks/CU
// x 16 waves = 32 waves/CU. R9/R10 lessons hold: NO nt stores, NO persistent
// grid (write stream relies on dispatch-order L2 line merging).

#define NATTR 85
#define NCH 255
#define TILE 64        // pixels per block
#define QPT 16         // float4 quads per channel tile (TILE/4)
#define NSTG (NCH * QPT)  // 4080 staging quads per full tile
#define NTHR 1024
#define NXCD 8

static constexpr int TOTROWS = (76 * 76 + 38 * 38 + 19 * 19) * 3;  // 22743

static __device__ __forceinline__ float sigmoidf_(float x) {
  return 1.0f / (1.0f + __expf(-x));
}

template <int SCALE>
struct Cfg {
  static constexpr int W = (SCALE == 0) ? 76 : (SCALE == 1) ? 38 : 19;
  static constexpr int HW = W * W;
  static constexpr int TILES = (HW + TILE - 1) / TILE;  // 91 / 23 / 6
  static constexpr float STRIDE = 608.0f / (float)W;
  static constexpr int ROWBASE =
      (SCALE == 0) ? 0 : (SCALE == 1) ? 76 * 76 * 3 : (76 * 76 * 3 + 38 * 38 * 3);
  static constexpr float AW0 = (SCALE == 0) ? 10.f : (SCALE == 1) ? 30.f : 116.f;
  static constexpr float AW1 = (SCALE == 0) ? 16.f : (SCALE == 1) ? 62.f : 156.f;
  static constexpr float AW2 = (SCALE == 0) ? 33.f : (SCALE == 1) ? 59.f : 373.f;
  static constexpr float AH0 = (SCALE == 0) ? 13.f : (SCALE == 1) ? 61.f : 90.f;
  static constexpr float AH1 = (SCALE == 0) ? 30.f : (SCALE == 1) ? 45.f : 198.f;
  static constexpr float AH2 = (SCALE == 0) ? 23.f : (SCALE == 1) ? 119.f : 326.f;
};

template <int SCALE>
static __device__ __forceinline__ float xf(int a, int attr, int p, float v,
                                           const float* __restrict__ sidf) {
  using C = Cfg<SCALE>;
  if (attr >= 5) return sigmoidf_(sidf[attr - 5] * v);  // 80/85 channels
  if (attr == 4) return sigmoidf_(v);
  if (attr == 2) {
    const float aw = (a == 0) ? C::AW0 : (a == 1) ? C::AW1 : C::AW2;
    return __expf(v) * aw;
  }
  if (attr == 3) {
    const float ah = (a == 0) ? C::AH0 : (a == 1) ? C::AH1 : C::AH2;
    return __expf(v) * ah;
  }
  const int h = p / C::W;  // constexpr W -> magic mul
  const int w = p - h * C::W;
  return (sigmoidf_(v) + (float)((attr == 0) ? w : h)) * C::STRIDE;
}

template <int SCALE>
static __device__ __forceinline__ void decode_tile(
    int b, int t, const float* __restrict__ x, float* __restrict__ out,
    const float* __restrict__ sidf, float* __restrict__ lds) {
  using C = Cfg<SCALE>;
  const int p0 = t * TILE;
  const int rem = C::HW - p0;
  const int np = rem < TILE ? rem : TILE;
  const size_t off = ((size_t)b * TOTROWS + C::ROWBASE + (size_t)p0 * 3) * NATTR;
  const int head = (int)((4 - (off & 3)) & 3);
  const int s = (4 - head) & 3;  // LDS shift so lds[s+head] is 16B-aligned
  const float* src = x + (size_t)b * ((size_t)C::HW * NCH) + p0;

  if ((C::HW % 4 == 0) && np == TILE) {
    // full tile: thread owns (channel c, quad v); 16 consecutive lanes share a
    // channel -> 256B contiguous per channel per wave-load
    float4 r[4];
    int cc[4], vv[4];
    bool act[4];
#pragma unroll
    for (int k = 0; k < 4; ++k) {
      int i = (int)threadIdx.x + NTHR * k;
      act[k] = i < NSTG;
      i = act[k] ? i : (NSTG - 1);  // clamp: branch-free in-bounds load
      cc[k] = i >> 4;
      vv[k] = i & 15;
      r[k] = *reinterpret_cast<const float4*>(src + (size_t)cc[k] * C::HW + 4 * vv[k]);
    }
#pragma unroll
    for (int k = 0; k < 4; ++k) {
      if (act[k]) {
        const int c = cc[k];
        const int a = c / NATTR;
        const int attr = c - a * NATTR;
        const int pb = p0 + 4 * vv[k];
        float* dl = lds + s + (4 * vv[k]) * NCH + c;  // [p][c], stride 255
        dl[0]       = xf<SCALE>(a, attr, pb + 0, r[k].x, sidf);
        dl[NCH]     = xf<SCALE>(a, attr, pb + 1, r[k].y, sidf);
        dl[2 * NCH] = xf<SCALE>(a, attr, pb + 2, r[k].z, sidf);
        dl[3 * NCH] = xf<SCALE>(a, attr, pb + 3, r[k].w, sidf);
      }
    }
  } else {
    // tail / odd-HW tile: scalar guarded (consecutive lanes -> consecutive p)
    for (int i = threadIdx.x; i < NCH * TILE; i += NTHR) {
      const int c = i >> 6;   // TILE = 64
      const int p = i & 63;
      if (p < np) {
        const int a = c / NATTR;
        const int attr = c - a * NATTR;
        const float v = src[(size_t)c * C::HW + p];
        lds[s + p * NCH + c] = xf<SCALE>(a, attr, p0 + p, v, sidf);
      }
    }
  }
  __syncthreads();

  float* dst = out + off;
  const int total = np * NCH;

  if ((np & 3) == 0) {
    if (threadIdx.x < head) dst[threadIdx.x] = lds[s + threadIdx.x];
    const int nvec = (total - head) >> 2;
    const float4* lv = reinterpret_cast<const float4*>(lds + s + head);  // aligned
    float4 tt[4];
    int vi[4];
    bool av[4];
#pragma unroll
    for (int k = 0; k < 4; ++k) {
      int v = (int)threadIdx.x + NTHR * k;
      av[k] = v < nvec;
      vi[k] = av[k] ? v : (nvec - 1);
      tt[k] = lv[vi[k]];
    }
#pragma unroll
    for (int k = 0; k < 4; ++k) {
      if (av[k]) *reinterpret_cast<float4*>(dst + head + 4 * vi[k]) = tt[k];
    }
    const int done = head + 4 * nvec;
    if (threadIdx.x < total - done) dst[done + threadIdx.x] = lds[s + done + threadIdx.x];
  } else {
    for (int j = threadIdx.x; j < total; j += NTHR) dst[j] = lds[s + j];
  }
}

__global__ __launch_bounds__(NTHR, 8) void yolo_all(
    const float* __restrict__ x0, const float* __restrict__ x1,
    const float* __restrict__ x2, const float* __restrict__ idf,
    float* __restrict__ out, int bs) {
  __shared__ __align__(16) float lds[TILE * NCH + 4];
  __shared__ float sidf[80];
  if (threadIdx.x < 80) sidf[threadIdx.x] = idf[threadIdx.x];
  __syncthreads();

  const int nb0 = Cfg<0>::TILES * bs;
  const int nb1 = Cfg<1>::TILES * bs;
  const int ntiles = nb0 + nb1 + Cfg<2>::TILES * bs;  // 1920 (bs=16), % 8 == 0

  // Bijective XCD-chunked swizzle: XCD (bid % 8, dispatch round-robin) owns
  // the contiguous tile chunk [x*cpx, (x+1)*cpx) -> every output line has
  // exactly one L2 owner; input chunk reads localize per-XCD.
  int blk = blockIdx.x;
  if ((ntiles & (NXCD - 1)) == 0) {
    const int cpx = ntiles / NXCD;
    blk = (blk & (NXCD - 1)) * cpx + (blk >> 3);
  }

  if (blk < nb0) {
    decode_tile<0>(blk / Cfg<0>::TILES, blk % Cfg<0>::TILES, x0, out, sidf, lds);
  } else if (blk < nb0 + nb1) {
    blk -= nb0;
    decode_tile<1>(blk / Cfg<1>::TILES, blk % Cfg<1>::TILES, x1, out, sidf, lds);
  } else {
    blk -= nb0 + nb1;
    decode_tile<2>(blk / Cfg<2>::TILES, blk % Cfg<2>::TILES, x2, out, sidf, lds);
  }
}

extern "C" void kernel_launch(void* const* d_in, const int* in_sizes, int n_in,
                              void* d_out, int out_size, void* d_ws, size_t ws_size,
                              hipStream_t stream) {
  const float* x0 = (const float*)d_in[0];
  const float* x1 = (const float*)d_in[1];
  const float* x2 = (const float*)d_in[2];
  const float* idf = (const float*)d_in[3];
  float* out = (float*)d_out;

  const int bs = in_sizes[0] / (NCH * 76 * 76);  // 16
  const int nb = (Cfg<0>::TILES + Cfg<1>::TILES + Cfg<2>::TILES) * bs;  // 120*bs

  yolo_all<<<dim3(nb), dim3(NTHR), 0, stream>>>(x0, x1, x2, idf, out, bs);
}